// Round 1
// baseline (352.185 us; speedup 1.0000x reference)
//
#include <hip/hip_runtime.h>

#define BIGV 1.0e10f
#define NN 512
#define MM 512
#define KD 64
#define BATCH 32
#define SROWS 16   // staged D diagonals per batch (LDS 16*512*4 = 32 KB)

// ---------------------------------------------------------------------------
// Kernel 1: pairwise squared distances, written in SKEWED (anti-diagonal)
// layout:  Dskew[b][i+j][i] = |x_i|^2 + |y_j|^2 - 2 x_i . y_j
// so the DP kernel's per-diagonal read is a coalesced 512-float row.
// Grid: (M/64, N/64, B), block (16,16). 64x64 output tile, K=64 fully staged.
// ---------------------------------------------------------------------------
__global__ __launch_bounds__(256) void dist_kernel(const float* __restrict__ x,
                                                   const float* __restrict__ y,
                                                   float* __restrict__ Dg) {
    const int b  = blockIdx.z;
    const int i0 = blockIdx.y * 64;
    const int j0 = blockIdx.x * 64;
    // transposed tiles: xs[k][i_local], row padded to 68 floats (16B-aligned,
    // breaks power-of-2 bank stride)
    __shared__ float xs[KD][68];
    __shared__ float ys[KD][68];
    const int tid = threadIdx.y * 16 + threadIdx.x;
    const float4* xb4 = (const float4*)(x + ((size_t)b * NN + i0) * KD);
    const float4* yb4 = (const float4*)(y + ((size_t)b * MM + j0) * KD);
#pragma unroll
    for (int q = 0; q < 4; ++q) {
        int f   = tid + 256 * q;   // 0..1023 float4s (64 rows x 16)
        int row = f >> 4;          // local i / j
        int c4  = f & 15;          // which float4 along K
        float4 xv = xb4[f];
        float4 yv = yb4[f];
        xs[c4 * 4 + 0][row] = xv.x; xs[c4 * 4 + 1][row] = xv.y;
        xs[c4 * 4 + 2][row] = xv.z; xs[c4 * 4 + 3][row] = xv.w;
        ys[c4 * 4 + 0][row] = yv.x; ys[c4 * 4 + 1][row] = yv.y;
        ys[c4 * 4 + 2][row] = yv.z; ys[c4 * 4 + 3][row] = yv.w;
    }
    __syncthreads();

    const int ty = threadIdx.y, tx = threadIdx.x;
    float acc[4][4] = {};
    float xn[4] = {}, yn[4] = {};
#pragma unroll 8
    for (int k = 0; k < KD; ++k) {
        float4 xv = *(const float4*)&xs[k][ty * 4];
        float4 yv = *(const float4*)&ys[k][tx * 4];
        float xa[4] = {xv.x, xv.y, xv.z, xv.w};
        float ya[4] = {yv.x, yv.y, yv.z, yv.w};
#pragma unroll
        for (int a = 0; a < 4; ++a) {
            xn[a] += xa[a] * xa[a];
            yn[a] += ya[a] * ya[a];
#pragma unroll
            for (int c = 0; c < 4; ++c) acc[a][c] += xa[a] * ya[c];
        }
    }
    float* Db = Dg + (size_t)b * 1023 * NN;
#pragma unroll
    for (int a = 0; a < 4; ++a) {
        int ii = i0 + ty * 4 + a;           // 0-based row (i-1)
#pragma unroll
        for (int c = 0; c < 4; ++c) {
            int jj = j0 + tx * 4 + c;       // 0-based col (j-1)
            Db[(size_t)(ii + jj) * NN + ii] = xn[a] + yn[c] - 2.0f * acc[a][c];
        }
    }
}

// ---------------------------------------------------------------------------
// Kernel 2: soft-DTW wavefront DP. One block per batch, thread t owns row
// i = t+1. Recurrence state carried in registers:
//   r2 = R[i, j-1]   = my previous val
//   r1 = R[i-1, j]   = neighbor's previous val (shfl_up; LDS at wave seams)
//   r0 = R[i-1, j-1] = previous r1
// D diagonals staged into LDS 16 at a time (coalesced float4 bulk copy).
// ---------------------------------------------------------------------------
__global__ __launch_bounds__(512) void dtw_kernel(const float* __restrict__ Dg,
                                                  float* __restrict__ out) {
    const int b    = blockIdx.x;
    const int t    = threadIdx.x;   // i = t+1
    const int lane = t & 63;
    const int wave = t >> 6;        // 0..7
    __shared__ float ldsD[SROWS][NN];
    __shared__ float bnd[2][8];     // wave-seam values, double-buffered by k&1
    const float* Db = Dg + (size_t)b * 1023 * NN;

    float r0 = (t == 0) ? 0.0f : BIGV;  // diag k-2 = 0 at index i-1
    float r1 = BIGV;                    // diag k-1 = 1 at index i-1
    float r2 = BIGV;                    // diag k-1 at index i (my prev val)
    float val = BIGV;

    for (int k = 2; k <= NN + MM; ++k) {
        const int kr = k - 2;
        if ((kr & (SROWS - 1)) == 0) {
            // stage rows kr .. kr+15 of Dskew (2048 float4s, 4 per thread)
            float4* dst = (float4*)&ldsD[0][0];
#pragma unroll
            for (int q = 0; q < 4; ++q) {
                int f   = t + 512 * q;   // 0..2047
                int row = f >> 7;        // 0..15
                int c4  = f & 127;
                int grow = kr + row;
                if (grow > 1022) grow = 1022;  // clamp (padding rows unused)
                dst[f] = *(const float4*)(Db + (size_t)grow * NN + c4 * 4);
            }
            __syncthreads();
        }
        const float d = ldsD[kr & (SROWS - 1)][t];
        const int j = k - (t + 1);
        const bool valid = (j >= 1) && (j <= MM);

        // softmin = m - ln(sum exp(m - r)), gamma = 1
        float m  = fminf(r0, fminf(r1, r2));
        float e0 = __builtin_amdgcn_exp2f((m - r0) * 1.44269504f);
        float e1 = __builtin_amdgcn_exp2f((m - r1) * 1.44269504f);
        float e2 = __builtin_amdgcn_exp2f((m - r2) * 1.44269504f);
        float sm = m - __builtin_amdgcn_logf(e0 + e1 + e2) * 0.69314718f;
        val = valid ? (d + sm) : BIGV;

        float nv = __shfl_up(val, 1, 64);
        if (lane == 63) bnd[k & 1][wave] = val;
        __syncthreads();
        float r1n;
        if (lane == 0) {
            r1n = (wave == 0) ? BIGV : bnd[k & 1][wave - 1];
        } else {
            r1n = nv;
        }
        r0 = r1;   // R[i-1, j-1] for next step = old R[i-1, j]
        r1 = r1n;
        r2 = val;
    }
    if (t == NN - 1) out[b] = val;   // R[N, M]
}

extern "C" void kernel_launch(void* const* d_in, const int* in_sizes, int n_in,
                              void* d_out, int out_size, void* d_ws, size_t ws_size,
                              hipStream_t stream) {
    const float* x = (const float*)d_in[0];
    const float* y = (const float*)d_in[1];
    float* out = (float*)d_out;
    float* Dg  = (float*)d_ws;  // needs 32*1023*512*4 = 67 MB of workspace

    dim3 gridD(MM / 64, NN / 64, BATCH), blockD(16, 16);
    dist_kernel<<<gridD, blockD, 0, stream>>>(x, y, Dg);
    dtw_kernel<<<BATCH, NN, 0, stream>>>(Dg, out);
}

// Round 2
// 216.188 us; speedup vs baseline: 1.6291x; 1.6291x over previous
//
#include <hip/hip_runtime.h>

#define BIGV 1.0e10f
#define L2E  1.44269504088896f   // log2(e)
#define LN2  0.69314718055994f
#define NN   512
#define MM   512
#define KD   64
#define BATCH 32
#define CHUNK 16
#define NCHUNK 36                 // ceil(575 / 16)
#define OFFS 5                    // inter-wave chunk offset (covers 63-step lag + ring margin)
#define NPHASE (NCHUNK + OFFS * 7)  // 71

// ---------------------------------------------------------------------------
// Kernel 1: pairwise squared distances -> skewed layout Dskew[b][i+j][i].
// GEMM-style 64x64 tile; output routed through LDS so the skewed-layout
// global stores are contiguous per diagonal (coalesced), instead of the
// stride-2048B scatter that made round-1 write-bound.
// ---------------------------------------------------------------------------
__global__ __launch_bounds__(256) void dist_kernel(const float* __restrict__ x,
                                                   const float* __restrict__ y,
                                                   float* __restrict__ Dg) {
    const int b  = blockIdx.z;
    const int i0 = blockIdx.y * 64;
    const int j0 = blockIdx.x * 64;
    __shared__ float xs[KD][68];
    __shared__ float ys[KD][68];
    __shared__ float sD[64][66];   // pad 66: diag read addr = i*65 + k, stride 65 (odd) -> conflict-free
    const int tid = threadIdx.y * 16 + threadIdx.x;
    const float4* xb4 = (const float4*)(x + ((size_t)b * NN + i0) * KD);
    const float4* yb4 = (const float4*)(y + ((size_t)b * MM + j0) * KD);
#pragma unroll
    for (int q = 0; q < 4; ++q) {
        int f   = tid + 256 * q;
        int row = f >> 4;
        int c4  = f & 15;
        float4 xv = xb4[f];
        float4 yv = yb4[f];
        xs[c4 * 4 + 0][row] = xv.x; xs[c4 * 4 + 1][row] = xv.y;
        xs[c4 * 4 + 2][row] = xv.z; xs[c4 * 4 + 3][row] = xv.w;
        ys[c4 * 4 + 0][row] = yv.x; ys[c4 * 4 + 1][row] = yv.y;
        ys[c4 * 4 + 2][row] = yv.z; ys[c4 * 4 + 3][row] = yv.w;
    }
    __syncthreads();

    const int ty = threadIdx.y, tx = threadIdx.x;
    float acc[4][4] = {};
    float xn[4] = {}, yn[4] = {};
#pragma unroll 8
    for (int k = 0; k < KD; ++k) {
        float4 xv = *(const float4*)&xs[k][ty * 4];
        float4 yv = *(const float4*)&ys[k][tx * 4];
        float xa[4] = {xv.x, xv.y, xv.z, xv.w};
        float ya[4] = {yv.x, yv.y, yv.z, yv.w};
#pragma unroll
        for (int a = 0; a < 4; ++a) {
            xn[a] += xa[a] * xa[a];
            yn[a] += ya[a] * ya[a];
#pragma unroll
            for (int c = 0; c < 4; ++c) acc[a][c] += xa[a] * ya[c];
        }
    }
    // stage tile into LDS
#pragma unroll
    for (int a = 0; a < 4; ++a)
#pragma unroll
        for (int c = 0; c < 4; ++c)
            sD[ty * 4 + a][tx * 4 + c] = xn[a] + yn[c] - 2.0f * acc[a][c];
    __syncthreads();

    // diagonal write-out: wave wv handles diagonals dl ≡ wv (mod 4)
    float* Db = Dg + (size_t)b * 1023 * NN;
    const int wv = tid >> 6;
    const int ln = tid & 63;
    const int k0 = i0 + j0;
#pragma unroll
    for (int it = 0; it < 32; ++it) {
        int dl = wv + 4 * it;                 // 0..127
        if (dl <= 126) {
            int il0 = dl > 63 ? dl - 63 : 0;
            int il1 = dl < 63 ? dl : 63;
            int il  = il0 + ln;
            if (il <= il1) {
                float v = sD[il][dl - il];
                Db[(size_t)(k0 + dl) * NN + i0 + il] = v;
            }
        }
    }
}

// ---------------------------------------------------------------------------
// Kernel 2: soft-DTW wavefront DP, wave-strip pipelined.
// Wave w owns rows i = 64w+1 .. 64w+64 (lane l -> row 64w+l+1).
// Wave-local step s: lane l computes column j = s - l + 1.
// Intra-wave neighbor via __shfl_up (no barrier). Inter-wave boundary row via
// LDS ring bnd[w][col & 127]; one __syncthreads per 16-step chunk.
// Phase p: wave w runs chunk c = p - 5w  (5-chunk offset covers the 63-step
// skew lag: consumer chunk c needs producer through step 16c+79 = chunk c+4).
// All R values carried scaled by log2(e): softmin' = m' - log2(sum 2^(m'-r')),
// val' = d*L2E + m' - lg. Final result multiplied by ln2.
// Invalid lanes (j<1 or j>512) need no masking: j<1 lanes stay ~BIG by
// construction; j>512 lanes produce values only ever consumed by other
// invalid lanes.
// ---------------------------------------------------------------------------
__global__ __launch_bounds__(512) void dtw_kernel(const float* __restrict__ Dg,
                                                  float* __restrict__ out) {
    const int b    = blockIdx.x;
    const int t    = threadIdx.x;
    const int lane = t & 63;
    const int w    = t >> 6;          // 0..7
    __shared__ float bnd[8][128];     // ring: boundary row values keyed by column & 127
    const float* Db = Dg + (size_t)b * 1023 * NN;
    const int off = t;                // column into skewed rows: 64w + lane

    float dvA[CHUNK], dvB[CHUNK], ringv[CHUNK];
    // prefetch chunk 0 (rows 64w + 0..15, all <= 463)
#pragma unroll
    for (int q = 0; q < CHUNK; ++q)
        dvA[q] = Db[(size_t)((w << 6) + q) * NN + off];

    float r0 = (w == 0 && lane == 0) ? 0.0f : BIGV * L2E;  // R[i-1, j-1]
    float r1 = BIGV * L2E;                                  // R[i-1, j]
    float r2 = BIGV * L2E;                                  // R[i, j-1]
    float val = BIGV * L2E;
    float res = 0.0f;

    auto run_chunk = [&](float (&dcur)[CHUNK], float (&dnext)[CHUNK], int c) {
        const int base = c * CHUNK;
        // prefetch chunk c+1 (clamp rows; garbage rows never used)
#pragma unroll
        for (int q = 0; q < CHUNK; ++q) {
            int row = (w << 6) + base + CHUNK + q;
            if (row > 1022) row = 1022;
            dnext[q] = Db[(size_t)row * NN + off];
        }
        // hoist ring reads off the per-step chain (cols base+2 .. base+17,
        // all written by producer >= 1 phase ago; same-phase producer writes
        // cols >= base+18, disjoint slots)
        if (w > 0) {
#pragma unroll
            for (int q = 0; q < CHUNK; ++q)
                ringv[q] = bnd[w - 1][(base + q + 2) & 127];
            if (c == 0 && lane == 0) r1 = bnd[w - 1][1];  // R[64w, 1]
        }
#pragma unroll
        for (int q = 0; q < CHUNK; ++q) {
            if (q == CHUNK - 1 && c == NCHUNK - 1) res = val;  // val(step 574)
            float d  = dcur[q];
            float m  = fminf(fminf(r0, r2), r1);               // v_min3
            float e0 = __builtin_amdgcn_exp2f(m - r0);
            float e1 = __builtin_amdgcn_exp2f(m - r1);
            float e2 = __builtin_amdgcn_exp2f(m - r2);
            float lg = __builtin_amdgcn_logf(e0 + e1 + e2);    // log2
            val = __builtin_fmaf(d, L2E, m) - lg;
            float nv = __shfl_up(val, 1, 64);
            r0 = r1;
            r1 = (lane == 0) ? ((w == 0) ? BIGV * L2E : ringv[q]) : nv;
            r2 = val;
            if (lane == 63 && w < 7) {
                int s = base + q;
                if (s >= 62) bnd[w][(s - 62) & 127] = val;     // col = s-62
            }
        }
    };

    for (int p = 0; p < NPHASE; ++p) {
        int c = p - OFFS * w;
        if (0 <= c && c < NCHUNK) {
            if (c & 1) run_chunk(dvB, dvA, c);
            else       run_chunk(dvA, dvB, c);
        }
        __syncthreads();
    }
    if (t == NN - 1) out[b] = res * LN2;   // R[512,512]
}

extern "C" void kernel_launch(void* const* d_in, const int* in_sizes, int n_in,
                              void* d_out, int out_size, void* d_ws, size_t ws_size,
                              hipStream_t stream) {
    const float* x = (const float*)d_in[0];
    const float* y = (const float*)d_in[1];
    float* out = (float*)d_out;
    float* Dg  = (float*)d_ws;  // 32*1023*512*4 = 67 MB

    dim3 gridD(MM / 64, NN / 64, BATCH), blockD(16, 16);
    dist_kernel<<<gridD, blockD, 0, stream>>>(x, y, Dg);
    dtw_kernel<<<BATCH, NN, 0, stream>>>(Dg, out);
}